// Round 14
// baseline (117.008 us; speedup 1.0000x reference)
//
#include <hip/hip_runtime.h>
#include <math.h>

#define D 512
#define NC 64
#define NQ 2048

typedef unsigned short u16;
typedef __attribute__((ext_vector_type(8))) short bf8;
typedef __attribute__((ext_vector_type(4))) float f4;

// ---- workspace float offsets ----
#define OFF_S    0
#define OFF_LH   32                       // 512x512 u16 L hi/lo
#define OFF_LL   (OFF_LH + 131072)
#define OFF_WH   (OFF_LL + 131072)        // 512x512 u16 W hi/lo (lo used on diag64 blocks)
#define OFF_WL   (OFF_WH + 131072)
#define OFF_ABH  (OFF_WL + 131072)        // 512x512 u16 Ubp hi/lo
#define OFF_ABL  (OFF_ABH + 131072)
#define OFF_UWH  (OFF_ABL + 131072)       // 512x512 u16 UW hi
#define OFF_GRAM (OFF_UWH + 131072)       // 64*28 fp32 packed upper-tri 7x7 Grams

#define GIX(i, j) ((i) * 7 - (i) * ((i) + 1) / 2 + (j))

__device__ inline float wred(float v) {
#pragma unroll
  for (int off = 32; off; off >>= 1) v += __shfl_down(v, off);
  return v;
}

// split fp32 into hi bf16 (truncated, so v-hi is exact) + lo bf16 (RN)
__device__ inline void split2(float v, u16& h, u16& l) {
  unsigned u = __float_as_uint(v);
  h = (u16)(u >> 16);
  float hf = __uint_as_float(u & 0xFFFF0000u);
  float r = v - hf;
  unsigned ru = __float_as_uint(r);
  l = (u16)((ru + 0x7FFFu + ((ru >> 16) & 1u)) >> 16);
}

__device__ inline void split4(float a0, float a1, float a2, float a3,
                              ushort4& h, ushort4& l) {
  u16 hh, ll;
  split2(a0, hh, ll); h.x = hh; l.x = ll;
  split2(a1, hh, ll); h.y = hh; l.y = ll;
  split2(a2, hh, ll); h.z = hh; l.z = ll;
  split2(a3, hh, ll); h.w = hh; l.w = ll;
}

#define MPAD 68
template <int N>
__device__ inline void lds_mm(float (*M)[MPAD], int ar, int ac, int br, int bc,
                              int cr, int cc, bool neg) {
  const int T = N / 16;
  int tx = (threadIdx.x & 15) * T, ty = (threadIdx.x >> 4) * T;
  float acc[T][T];
#pragma unroll
  for (int i = 0; i < T; ++i)
#pragma unroll
    for (int j = 0; j < T; ++j) acc[i][j] = 0.f;
#pragma unroll 8
  for (int k = 0; k < N; ++k) {
    float a[T], b[T];
#pragma unroll
    for (int i = 0; i < T; ++i) a[i] = M[ar + ty + i][ac + k];
#pragma unroll
    for (int j = 0; j < T; ++j) b[j] = M[br + k][bc + tx + j];
#pragma unroll
    for (int i = 0; i < T; ++i)
#pragma unroll
      for (int j = 0; j < T; ++j) acc[i][j] += a[i] * b[j];
  }
#pragma unroll
  for (int i = 0; i < T; ++i)
#pragma unroll
    for (int j = 0; j < T; ++j)
      M[cr + ty + i][cc + tx + j] = neg ? -acc[i][j] : acc[i][j];
}

// In-LDS 64x64 lower-tri inversion; scratch cleaned -> exact inverse, zero upper.
__device__ inline void inv64(float (*M)[MPAD], int tid) {
  {
    float x[16];
    int q = tid >> 4, col = tid & 15;
    if (tid < 64) {
      int b = q << 4;
#pragma unroll
      for (int i = 0; i < 16; ++i) {
        float acc = 0.f;
#pragma unroll
        for (int k = 0; k < i; ++k) acc += M[b + i][b + k] * x[k];
        x[i] = (((i == col) ? 1.f : 0.f) - acc) / M[b + i][b + i];
      }
    }
    __syncthreads();
    if (tid < 64) {
      int b = q << 4;
#pragma unroll
      for (int i = 0; i < 16; ++i) M[b + i][b + col] = x[i];
    }
    __syncthreads();
  }
  for (int pp = 0; pp < 2; ++pp) {
    int r0 = 32 * pp;
    lds_mm<16>(M, r0 + 16, r0, r0, r0, r0, r0 + 16, false);
  }
  __syncthreads();
  for (int pp = 0; pp < 2; ++pp) {
    int r0 = 32 * pp;
    lds_mm<16>(M, r0 + 16, r0 + 16, r0, r0 + 16, r0 + 16, r0, true);
  }
  __syncthreads();
  for (int idx = tid; idx < 512; idx += 256) {     // zero level-16 scratch
    int t2 = idx >> 8, r = (idx >> 4) & 15, c = idx & 15;
    M[32 * t2 + r][32 * t2 + 16 + c] = 0.f;
  }
  __syncthreads();
  lds_mm<32>(M, 32, 0, 0, 0, 0, 32, false);
  __syncthreads();
  lds_mm<32>(M, 32, 32, 0, 32, 32, 0, true);
  __syncthreads();
  for (int idx = tid; idx < 1024; idx += 256) {    // zero level-32 scratch
    int r = idx >> 5, c = idx & 31;
    M[r][32 + c] = 0.f;
  }
  __syncthreads();
}

// Prep (329 blocks): 0..7 diag64-inv -> W diag (h/l); 8..71 classprep;
// 72 scalars + Gram zero; 73..328 L-split (also zero Wh upper).
__global__ __launch_bounds__(256) void k_prep(const float* __restrict__ diag,
                                              const float* __restrict__ low,
                                              const float* __restrict__ Xs,
                                              const float* __restrict__ m,
                                              const float* __restrict__ kp,
                                              const float* __restrict__ nup,
                                              u16* __restrict__ Lh, u16* __restrict__ Ll,
                                              u16* __restrict__ ABh, u16* __restrict__ ABl,
                                              u16* __restrict__ Wh, u16* __restrict__ Wl,
                                              float* __restrict__ S, float* __restrict__ Gram) {
  __shared__ float M[64][MPAD];
  int bid = blockIdx.x, tid = threadIdx.x;
  if (bid < 8) {
    int p = bid * 64;
    for (int idx = tid; idx < 4096; idx += 256) {
      int r = idx >> 6, c = idx & 63;
      float v;
      if (r == c)      v = fabsf(diag[p + r]);
      else if (r > c)  v = low[(size_t)(p + r) * D + p + c];
      else             v = 0.f;
      M[r][c] = v;
    }
    __syncthreads();
    inv64(M, tid);
    for (int idx = tid; idx < 1024; idx += 256) {
      int r = idx >> 4, c4 = (idx & 15) << 2;
      ushort4 hh, ll;
      split4(M[r][c4 + 0], M[r][c4 + 1], M[r][c4 + 2], M[r][c4 + 3], hh, ll);
      size_t gi = (size_t)(p + r) * D + p + c4;
      *reinterpret_cast<ushort4*>(Wh + gi) = hh;
      *reinterpret_cast<ushort4*>(Wl + gi) = ll;
    }
  } else if (bid < 72) {
    int c = bid - 8;
    if (tid < 128) {
      float kappa = kp[0];
      float kn = fabsf(kappa) + 1e-6f + 5.0f;
      float xw = 5.0f / kn;
      float mw = fabsf(kappa + 1e-6f) / kn;
      float sw = sqrtf((fabsf(kappa) + 1e-6f) / kn);
      const float is5 = 0.44721359549995793f;
      int d4 = tid;
      float xs[5][4];
#pragma unroll
      for (int s = 0; s < 5; ++s) {
        float4 v = reinterpret_cast<const float4*>(Xs + (size_t)(c * 5 + s) * D)[d4];
        xs[s][0] = v.x; xs[s][1] = v.y; xs[s][2] = v.z; xs[s][3] = v.w;
      }
      float4 mvv = reinterpret_cast<const float4*>(m)[d4];
      float mv[4] = {mvv.x, mvv.y, mvv.z, mvv.w};
      float rows[8][4];
#pragma unroll
      for (int e = 0; e < 4; ++e) {
        float xm = (xs[0][e] + xs[1][e] + xs[2][e] + xs[3][e] + xs[4][e]) * 0.2f;
#pragma unroll
        for (int s = 0; s < 5; ++s) rows[s][e] = xs[s][e] * is5;
        rows[5][e] = sw * (xm - mv[e]);
        rows[6][e] = mw * mv[e] + xw * xm;
        rows[7][e] = 0.f;
      }
#pragma unroll
      for (int s = 0; s < 8; ++s) {
        ushort4 hh, ll;
        split4(rows[s][0], rows[s][1], rows[s][2], rows[s][3], hh, ll);
        size_t gi = (size_t)(c * 8 + s) * D + 4 * tid;
        *reinterpret_cast<ushort4*>(ABh + gi) = hh;
        *reinterpret_cast<ushort4*>(ABl + gi) = ll;
      }
    }
  } else if (bid == 72) {
    for (int i = tid; i < NC * 28; i += 256) Gram[i] = 0.f;
    if (tid >= 64) return;
    float part = 0.f;
    for (int i = tid; i < D; i += 64) part += logf(fabsf(diag[i]));
    part = wred(part);
    if (tid != 0) return;
    float lda = 2.f * part;
    float kappa = kp[0], nu = nup[0];
    float kn = fabsf(kappa) + 1e-6f + 5.0f;
    float sp = fmaxf(nu, (float)(D - 1) + 1e-6f) + 5.0f - (float)D + 2.0f;
    float bias_shared = lgammaf(0.5f * (sp + (float)D)) - lgammaf(0.5f * sp)
                      - 0.5f * (float)D * logf(sp);
    float scale = kn * sp / (kn + 1.0f);
    S[3] = bias_shared;
    S[8] = 1.f / scale;
    S[9] = (float)D * logf(scale) + lda;
    S[10] = 0.5f * (sp + (float)D);
    S[11] = 1.f / sp;
  } else {
    int t = (bid - 73) * 1024 + tid * 4;
    int i = t >> 9, j = t & 511;
    float4 lv = *reinterpret_cast<const float4*>(low + t);
    float a[4] = {lv.x, lv.y, lv.z, lv.w};
    float dv = diag[i];
    float o[4];
#pragma unroll
    for (int e = 0; e < 4; ++e) {
      int jj = j + e;
      o[e] = (i == jj) ? fabsf(dv) : (i > jj ? a[e] : 0.f);
    }
    ushort4 hh, ll;
    split4(o[0], o[1], o[2], o[3], hh, ll);
    *reinterpret_cast<ushort4*>(Lh + t) = hh;
    *reinterpret_cast<ushort4*>(Ll + t) = ll;
    if (i < j) Wh[t] = 0;   // zero W strict upper (hi)
    if (i < j + 3) {        // per-element upper zeroing for the vector span
#pragma unroll
      for (int e = 0; e < 4; ++e) if (i < j + e) Wh[t + e] = 0;
    }
  }
}

// W = L^{-1} column-panel solve (R12-proven). Panel J owns cols [32J,32J+32).
__global__ __launch_bounds__(256) void k_solve(const u16* __restrict__ Lh,
                                               const u16* __restrict__ Ll,
                                               u16* __restrict__ Wh,
                                               const u16* __restrict__ Wl) {
  __shared__ __align__(16) u16 XTh[32][520];
  __shared__ __align__(16) u16 XTl[32][520];
  __shared__ __align__(16) u16 STh[32][72];
  __shared__ __align__(16) u16 STl[32][72];
  int J = blockIdx.x;
  int i0 = J >> 1;
  int tid = threadIdx.x, w = tid >> 6, lane = tid & 63;
  int lr = lane & 15, kq = lane >> 4;
  for (int idx = tid; idx < 64 * 32; idx += 256) {
    int r = idx >> 5, c = idx & 31;
    size_t gi = (size_t)(64 * i0 + r) * D + 64 * i0 + (J & 1) * 32 + c;
    XTh[c][64 * i0 + r] = Wh[gi];
    XTl[c][64 * i0 + r] = Wl[gi];
  }
  __syncthreads();
  for (int i = i0 + 1; i < 8; ++i) {
    f4 acc[2];
    acc[0] = (f4){0.f, 0.f, 0.f, 0.f};
    acc[1] = (f4){0.f, 0.f, 0.f, 0.f};
    for (int k = i0; k < i; ++k) {
#pragma unroll
      for (int kk = 0; kk < 2; ++kk) {
        size_t ga = (size_t)(64 * i + w * 16 + lr) * D + 64 * k + kk * 32 + kq * 8;
        bf8 ah = *reinterpret_cast<const bf8*>(Lh + ga);
        bf8 al = *reinterpret_cast<const bf8*>(Ll + ga);
#pragma unroll
        for (int nf = 0; nf < 2; ++nf) {
          bf8 bh = *reinterpret_cast<const bf8*>(&XTh[nf * 16 + lr][64 * k + kk * 32 + kq * 8]);
          bf8 bl = *reinterpret_cast<const bf8*>(&XTl[nf * 16 + lr][64 * k + kk * 32 + kq * 8]);
          acc[nf] = __builtin_amdgcn_mfma_f32_16x16x32_bf16(ah, bh, acc[nf], 0, 0, 0);
          acc[nf] = __builtin_amdgcn_mfma_f32_16x16x32_bf16(al, bh, acc[nf], 0, 0, 0);
          acc[nf] = __builtin_amdgcn_mfma_f32_16x16x32_bf16(ah, bl, acc[nf], 0, 0, 0);
        }
      }
    }
#pragma unroll
    for (int nf = 0; nf < 2; ++nf)
#pragma unroll
      for (int reg = 0; reg < 4; ++reg) {
        float v = -acc[nf][reg];
        u16 hh, ll; split2(v, hh, ll);
        int c = nf * 16 + lr, r = w * 16 + kq * 4 + reg;
        STh[c][r] = hh; STl[c][r] = ll;
      }
    __syncthreads();
    f4 acc2[2];
    acc2[0] = (f4){0.f, 0.f, 0.f, 0.f};
    acc2[1] = (f4){0.f, 0.f, 0.f, 0.f};
#pragma unroll
    for (int kk = 0; kk < 2; ++kk) {
      size_t ga = (size_t)(64 * i + w * 16 + lr) * D + 64 * i + kk * 32 + kq * 8;
      bf8 ah = *reinterpret_cast<const bf8*>(Wh + ga);
      bf8 al = *reinterpret_cast<const bf8*>(Wl + ga);
#pragma unroll
      for (int nf = 0; nf < 2; ++nf) {
        bf8 bh = *reinterpret_cast<const bf8*>(&STh[nf * 16 + lr][kk * 32 + kq * 8]);
        bf8 bl = *reinterpret_cast<const bf8*>(&STl[nf * 16 + lr][kk * 32 + kq * 8]);
        acc2[nf] = __builtin_amdgcn_mfma_f32_16x16x32_bf16(ah, bh, acc2[nf], 0, 0, 0);
        acc2[nf] = __builtin_amdgcn_mfma_f32_16x16x32_bf16(ah, bl, acc2[nf], 0, 0, 0);
        acc2[nf] = __builtin_amdgcn_mfma_f32_16x16x32_bf16(al, bh, acc2[nf], 0, 0, 0);
      }
    }
#pragma unroll
    for (int nf = 0; nf < 2; ++nf)
#pragma unroll
      for (int reg = 0; reg < 4; ++reg) {
        float v = acc2[nf][reg];
        u16 hh, ll; split2(v, hh, ll);
        int r = w * 16 + kq * 4 + reg, c = nf * 16 + lr;
        Wh[(size_t)(64 * i + r) * D + 32 * J + c] = hh;
        XTh[c][64 * i + r] = hh; XTl[c][64 * i + r] = ll;
      }
    __syncthreads();
  }
}

// UW GEMM (MFMA split-bf16, 2-pass): UW = Ubp @ W^T (512 rows, tri-clipped)
// + 7x7 class Grams. Grid (8 col-strips, 8 row-blocks).
__global__ __launch_bounds__(256) void k_mf1s(const u16* __restrict__ ABh, const u16* __restrict__ ABl,
                                              const u16* __restrict__ Wh,
                                              u16* __restrict__ UWh,
                                              float* __restrict__ Gram) {
  __shared__ float Csh[64][68];
  int tid = threadIdx.x, w = tid >> 6, lane = tid & 63;
  int bn = (7 - (int)blockIdx.x) * 64;
  int m0 = blockIdx.y * 64 + w * 16;
  int lr = lane & 15, kof = (lane >> 4) * 8;
  const u16* ah_p = ABh + (size_t)(m0 + lr) * D + kof;
  const u16* al_p = ABl + (size_t)(m0 + lr) * D + kof;
  const u16* bh_p = Wh + (size_t)(bn + lr) * D + kof;
  f4 acc[4];
#pragma unroll
  for (int nf = 0; nf < 4; ++nf) acc[nf] = (f4){0.f, 0.f, 0.f, 0.f};
  int Klim = bn + 64;
#pragma unroll 2
  for (int k0 = 0; k0 < Klim; k0 += 32) {
    bf8 ah = *reinterpret_cast<const bf8*>(ah_p + k0);
    bf8 al = *reinterpret_cast<const bf8*>(al_p + k0);
    bf8 bh[4];
#pragma unroll
    for (int nf = 0; nf < 4; ++nf)
      bh[nf] = *reinterpret_cast<const bf8*>(bh_p + (size_t)nf * 16 * D + k0);
#pragma unroll
    for (int nf = 0; nf < 4; ++nf)
      acc[nf] = __builtin_amdgcn_mfma_f32_16x16x32_bf16(ah, bh[nf], acc[nf], 0, 0, 0);
#pragma unroll
    for (int nf = 0; nf < 4; ++nf)
      acc[nf] = __builtin_amdgcn_mfma_f32_16x16x32_bf16(al, bh[nf], acc[nf], 0, 0, 0);
  }
#pragma unroll
  for (int reg = 0; reg < 4; ++reg) {
    int row = m0 + ((lane >> 4) << 2) + reg;
#pragma unroll
    for (int nf = 0; nf < 4; ++nf) {
      float v = acc[nf][reg];
      u16 hh, ll; split2(v, hh, ll);
      UWh[(size_t)row * D + bn + nf * 16 + lr] = hh;
      Csh[(row - blockIdx.y * 64)][nf * 16 + lr] = v;
    }
  }
  __syncthreads();
  if (tid < 224) {
    const int PI[28] = {0,0,0,0,0,0,0, 1,1,1,1,1,1, 2,2,2,2,2, 3,3,3,3, 4,4,4, 5,5, 6};
    const int PJ[28] = {0,1,2,3,4,5,6, 1,2,3,4,5,6, 2,3,4,5,6, 3,4,5,6, 4,5,6, 5,6, 6};
    int cl = tid / 28, p = tid % 28;
    const float* ri = Csh[cl * 8 + PI[p]];
    const float* rj = Csh[cl * 8 + PJ[p]];
    float s = 0.f;
#pragma unroll
    for (int c4 = 0; c4 < 64; c4 += 4) {
      float4 a = *reinterpret_cast<const float4*>(&ri[c4]);
      float4 b = *reinterpret_cast<const float4*>(&rj[c4]);
      s += a.x * b.x + a.y * b.y + a.z * b.z + a.w * b.w;
    }
    atomicAdd(&Gram[(blockIdx.y * 8 + cl) * 28 + p], s);
  }
}

// Fused query kernel: per block 16 Q-rows.
// P1: Y = Xq @ W^T (tri-clipped, fp32->h/l on the fly) -> LDS; aq local.
// P2: 64 class Choleskys (tid<64). P3: T2 = Y @ UW^T. P4: epilogue -> out.
__global__ __launch_bounds__(256) void k_mf2f(const float* __restrict__ Xq,
                                              const u16* __restrict__ Wh,
                                              const u16* __restrict__ UWh,
                                              const float* __restrict__ Gram,
                                              const float* __restrict__ S,
                                              float* __restrict__ out) {
  __shared__ __align__(16) char shmem[16 * 520 * 4];  // Yh/Yl (u16) then T2s (f32)
  __shared__ float asq[16];
  __shared__ float PRo[64][15], PRd[64][6], Psv[64][6], Pb[64], Ph[64];
  u16 (*Yh)[520] = reinterpret_cast<u16(*)[520]>(shmem);
  u16 (*Yl)[520] = reinterpret_cast<u16(*)[520]>(shmem + 16 * 520 * 2);
  int tid = threadIdx.x, w = tid >> 6, lane = tid & 63;
  int lr = lane & 15, kq = lane >> 4, kof = kq * 8;
  int q0 = blockIdx.x * 16;
  if (tid < 16) asq[tid] = 0.f;
  __syncthreads();
  // ---- P1: Y ----
  f4 acc[8];
#pragma unroll
  for (int j = 0; j < 8; ++j) acc[j] = (f4){0.f, 0.f, 0.f, 0.f};
  int klim[8];
#pragma unroll
  for (int j = 0; j < 8; ++j) {
    int bn = 16 * (w + 4 * j);
    klim[j] = (((bn + 47) >> 5) << 5);
  }
  const float* xrow = Xq + (size_t)(q0 + lr) * D;
  for (int k0 = 0; k0 < klim[7]; k0 += 32) {
    float4 a0 = *reinterpret_cast<const float4*>(xrow + k0 + kof);
    float4 a1 = *reinterpret_cast<const float4*>(xrow + k0 + kof + 4);
    float av[8] = {a0.x, a0.y, a0.z, a0.w, a1.x, a1.y, a1.z, a1.w};
    bf8 ah, al;
#pragma unroll
    for (int e = 0; e < 8; ++e) {
      u16 hh, ll; split2(av[e], hh, ll);
      ah[e] = (short)hh; al[e] = (short)ll;
    }
#pragma unroll
    for (int j = 0; j < 8; ++j) {
      if (k0 < klim[j]) {
        const u16* bp = Wh + (size_t)(16 * (w + 4 * j) + lr) * D + k0 + kof;
        bf8 bh = *reinterpret_cast<const bf8*>(bp);
        acc[j] = __builtin_amdgcn_mfma_f32_16x16x32_bf16(ah, bh, acc[j], 0, 0, 0);
        acc[j] = __builtin_amdgcn_mfma_f32_16x16x32_bf16(al, bh, acc[j], 0, 0, 0);
      }
    }
  }
  float sq[4] = {0.f, 0.f, 0.f, 0.f};
#pragma unroll
  for (int j = 0; j < 8; ++j) {
    int bn = 16 * (w + 4 * j);
#pragma unroll
    for (int reg = 0; reg < 4; ++reg) {
      float v = acc[j][reg];
      u16 hh, ll; split2(v, hh, ll);
      Yh[kq * 4 + reg][bn + lr] = hh;
      Yl[kq * 4 + reg][bn + lr] = ll;
      sq[reg] += v * v;
    }
  }
#pragma unroll
  for (int reg = 0; reg < 4; ++reg) {
#pragma unroll
    for (int mk = 1; mk < 16; mk <<= 1) sq[reg] += __shfl_xor(sq[reg], mk);
    if (lr == 0) atomicAdd(&asq[kq * 4 + reg], sq[reg]);
  }
  __syncthreads();
  // ---- P2: Cholesky prologue (tid<64, one class each) ----
  if (tid < 64) {
    int c = tid;
    float Gv[28];
#pragma unroll
    for (int p = 0; p < 28; ++p) Gv[p] = Gram[c * 28 + p];
    float R[6][6];
    float logdetM = 0.f;
#pragma unroll
    for (int i = 0; i < 6; ++i) {
      float s = Gv[GIX(i, i)] + 1.f;
#pragma unroll
      for (int k = 0; k < i; ++k) s -= R[i][k] * R[i][k];
      float rii = sqrtf(s);
      R[i][i] = rii;
      logdetM += logf(rii);
      float inv = 1.f / rii;
      PRd[c][i] = inv;
#pragma unroll
      for (int r = i + 1; r < 6; ++r) {
        float s2 = Gv[GIX(i, r)];
#pragma unroll
        for (int k = 0; k < i; ++k) s2 -= R[r][k] * R[i][k];
        R[r][i] = s2 * inv;
      }
    }
#pragma unroll
    for (int i = 1; i < 6; ++i)
#pragma unroll
      for (int k = 0; k < i; ++k)
        PRo[c][i * (i - 1) / 2 + k] = R[i][k];
#pragma unroll
    for (int j = 0; j < 6; ++j) Psv[c][j] = Gv[GIX(j, 6)];
    Ph[c] = Gv[27];
    Pb[c] = S[3] - 0.5f * (S[9] + 2.f * logdetM);
  }
  // ---- P3: T2 = Y @ UW^T ----
  f4 acc2[8];
#pragma unroll
  for (int j = 0; j < 8; ++j) acc2[j] = (f4){0.f, 0.f, 0.f, 0.f};
  for (int k0 = 0; k0 < D; k0 += 32) {
    bf8 ah = *reinterpret_cast<const bf8*>(&Yh[lr][k0 + kof]);
    bf8 al = *reinterpret_cast<const bf8*>(&Yl[lr][k0 + kof]);
#pragma unroll
    for (int j = 0; j < 8; ++j) {
      const u16* bp = UWh + (size_t)(128 * w + 16 * j + lr) * D + k0 + kof;
      bf8 bh = *reinterpret_cast<const bf8*>(bp);
      acc2[j] = __builtin_amdgcn_mfma_f32_16x16x32_bf16(ah, bh, acc2[j], 0, 0, 0);
      acc2[j] = __builtin_amdgcn_mfma_f32_16x16x32_bf16(al, bh, acc2[j], 0, 0, 0);
    }
  }
  __syncthreads();   // all Yh/Yl reads done
  // ---- P4: dump T2 (aliases Y LDS) + epilogue ----
  float (*T2s)[520] = reinterpret_cast<float(*)[520]>(shmem);
#pragma unroll
  for (int j = 0; j < 8; ++j)
#pragma unroll
    for (int reg = 0; reg < 4; ++reg)
      T2s[kq * 4 + reg][128 * w + 16 * j + lr] = acc2[j][reg];
  __syncthreads();
  float s8 = S[8], s10 = S[10], s11 = S[11];
  int r_ = tid & 15, cg = tid >> 4;
  float aqv = asq[r_];
#pragma unroll
  for (int cc = 0; cc < 4; ++cc) {
    int c = cg * 4 + cc;
    const float* t = &T2s[r_][c * 8];
    float e[6];
#pragma unroll
    for (int j = 0; j < 6; ++j) e[j] = t[j] - Psv[c][j];
    const float* o = PRo[c];
    const float* dg = PRd[c];
    float z0 = e[0] * dg[0];
    float z1 = (e[1] - o[0] * z0) * dg[1];
    float z2 = (e[2] - o[1] * z0 - o[2] * z1) * dg[2];
    float z3 = (e[3] - o[3] * z0 - o[4] * z1 - o[5] * z2) * dg[3];
    float z4 = (e[4] - o[6] * z0 - o[7] * z1 - o[8] * z2 - o[9] * z3) * dg[4];
    float z5 = (e[5] - o[10] * z0 - o[11] * z1 - o[12] * z2 - o[13] * z3 - o[14] * z4) * dg[5];
    float quad = z0 * z0 + z1 * z1 + z2 * z2 + z3 * z3 + z4 * z4 + z5 * z5;
    float dist = (aqv - 2.f * t[6] + Ph[c] - quad) * s8;
    out[(size_t)(q0 + r_) * NC + c] = Pb[c] - s10 * log1pf(dist * s11);
  }
}

extern "C" void kernel_launch(void* const* d_in, const int* in_sizes, int n_in,
                              void* d_out, int out_size, void* d_ws, size_t ws_size,
                              hipStream_t stream) {
  const float* Xs   = (const float*)d_in[0];
  const float* Xq   = (const float*)d_in[2];
  const float* m    = (const float*)d_in[3];
  const float* kap  = (const float*)d_in[4];
  const float* nu   = (const float*)d_in[5];
  const float* diag = (const float*)d_in[6];
  const float* low  = (const float*)d_in[7];
  float* ws = (float*)d_ws;

  float* S    = ws + OFF_S;
  u16*   Lh   = (u16*)(ws + OFF_LH);
  u16*   Ll   = (u16*)(ws + OFF_LL);
  u16*   Wh   = (u16*)(ws + OFF_WH);
  u16*   Wl   = (u16*)(ws + OFF_WL);
  u16*   ABh  = (u16*)(ws + OFF_ABH);
  u16*   ABl  = (u16*)(ws + OFF_ABL);
  u16*   UWh  = (u16*)(ws + OFF_UWH);
  float* Gram = ws + OFF_GRAM;

  hipLaunchKernelGGL(k_prep, dim3(329), dim3(256), 0, stream,
                     diag, low, Xs, m, kap, nu, Lh, Ll, ABh, ABl, Wh, Wl, S, Gram);
  hipLaunchKernelGGL(k_solve, dim3(16), dim3(256), 0, stream, Lh, Ll, Wh, Wl);
  hipLaunchKernelGGL(k_mf1s, dim3(8, 8), dim3(256), 0, stream,
                     ABh, ABl, Wh, UWh, Gram);
  hipLaunchKernelGGL(k_mf2f, dim3(NQ / 16), dim3(256), 0, stream,
                     Xq, Wh, UWh, Gram, S, (float*)d_out);
}

// Round 15
// 76.988 us; speedup vs baseline: 1.5198x; 1.5198x over previous
//
#include <hip/hip_runtime.h>
#include <math.h>

#define D 512
#define NC 64
#define NQ 2048

typedef unsigned short u16;
typedef __attribute__((ext_vector_type(8))) short bf8;
typedef __attribute__((ext_vector_type(4))) float f4;

// ---- workspace float offsets ----
#define OFF_S    0
#define OFF_ABH  32                       // 2560x512 u16 (rows 0-511 Ubp, 512+ Xq) hi
#define OFF_ABL  (OFF_ABH + 655360)
#define OFF_LH   (OFF_ABL + 655360)       // 512x512 u16 L hi/lo
#define OFF_LL   (OFF_LH + 131072)
#define OFF_WH   (OFF_LL + 131072)        // 512x512 u16 W hi/lo (lo valid on diag64 blocks)
#define OFF_WL   (OFF_WH + 131072)
#define OFF_YYH  (OFF_WL + 131072)        // 2560x512 u16 YY hi; lo only rows>=512
#define OFF_YYL  (OFF_YYH + 655360)
#define OFF_AQ   (OFF_YYL + 655360)       // 2048 fp32
#define OFF_GRAM (OFF_AQ + NQ)            // 64*28 fp32 packed upper-tri 7x7 Grams

#define GIX(i, j) ((i) * 7 - (i) * ((i) + 1) / 2 + (j))

__device__ inline float wred(float v) {
#pragma unroll
  for (int off = 32; off; off >>= 1) v += __shfl_down(v, off);
  return v;
}

// split fp32 into hi bf16 (truncated, so v-hi is exact) + lo bf16 (RN)
__device__ inline void split2(float v, u16& h, u16& l) {
  unsigned u = __float_as_uint(v);
  h = (u16)(u >> 16);
  float hf = __uint_as_float(u & 0xFFFF0000u);
  float r = v - hf;
  unsigned ru = __float_as_uint(r);
  l = (u16)((ru + 0x7FFFu + ((ru >> 16) & 1u)) >> 16);
}

__device__ inline void split4(float a0, float a1, float a2, float a3,
                              ushort4& h, ushort4& l) {
  u16 hh, ll;
  split2(a0, hh, ll); h.x = hh; l.x = ll;
  split2(a1, hh, ll); h.y = hh; l.y = ll;
  split2(a2, hh, ll); h.z = hh; l.z = ll;
  split2(a3, hh, ll); h.w = hh; l.w = ll;
}

#define MPAD 68
template <int N>
__device__ inline void lds_mm(float (*M)[MPAD], int ar, int ac, int br, int bc,
                              int cr, int cc, bool neg) {
  const int T = N / 16;
  int tx = (threadIdx.x & 15) * T, ty = (threadIdx.x >> 4) * T;
  float acc[T][T];
#pragma unroll
  for (int i = 0; i < T; ++i)
#pragma unroll
    for (int j = 0; j < T; ++j) acc[i][j] = 0.f;
#pragma unroll 8
  for (int k = 0; k < N; ++k) {
    float a[T], b[T];
#pragma unroll
    for (int i = 0; i < T; ++i) a[i] = M[ar + ty + i][ac + k];
#pragma unroll
    for (int j = 0; j < T; ++j) b[j] = M[br + k][bc + tx + j];
#pragma unroll
    for (int i = 0; i < T; ++i)
#pragma unroll
      for (int j = 0; j < T; ++j) acc[i][j] += a[i] * b[j];
  }
#pragma unroll
  for (int i = 0; i < T; ++i)
#pragma unroll
    for (int j = 0; j < T; ++j)
      M[cr + ty + i][cc + tx + j] = neg ? -acc[i][j] : acc[i][j];
}

// In-LDS 64x64 lower-tri inversion; scratch cleaned -> exact inverse, zero upper.
__device__ inline void inv64(float (*M)[MPAD], int tid) {
  {
    float x[16];
    int q = tid >> 4, col = tid & 15;
    if (tid < 64) {
      int b = q << 4;
#pragma unroll
      for (int i = 0; i < 16; ++i) {
        float acc = 0.f;
#pragma unroll
        for (int k = 0; k < i; ++k) acc += M[b + i][b + k] * x[k];
        x[i] = (((i == col) ? 1.f : 0.f) - acc) / M[b + i][b + i];
      }
    }
    __syncthreads();
    if (tid < 64) {
      int b = q << 4;
#pragma unroll
      for (int i = 0; i < 16; ++i) M[b + i][b + col] = x[i];
    }
    __syncthreads();
  }
  for (int pp = 0; pp < 2; ++pp) {
    int r0 = 32 * pp;
    lds_mm<16>(M, r0 + 16, r0, r0, r0, r0, r0 + 16, false);
  }
  __syncthreads();
  for (int pp = 0; pp < 2; ++pp) {
    int r0 = 32 * pp;
    lds_mm<16>(M, r0 + 16, r0 + 16, r0, r0 + 16, r0 + 16, r0, true);
  }
  __syncthreads();
  for (int idx = tid; idx < 512; idx += 256) {     // zero level-16 scratch
    int t2 = idx >> 8, r = (idx >> 4) & 15, c = idx & 15;
    M[32 * t2 + r][32 * t2 + 16 + c] = 0.f;
  }
  __syncthreads();
  lds_mm<32>(M, 32, 0, 0, 0, 0, 32, false);
  __syncthreads();
  lds_mm<32>(M, 32, 32, 0, 32, 32, 0, true);
  __syncthreads();
  for (int idx = tid; idx < 1024; idx += 256) {    // zero level-32 scratch
    int r = idx >> 5, c = idx & 31;
    M[r][32 + c] = 0.f;
  }
  __syncthreads();
}

// Fused prep (457 blocks, heavy roles FIRST):
//   0..7    : invert 64x64 diag block of L in LDS -> W diag (h/l)
//   8..71   : classprep -> ABh/ABl rows c*8.. (float4 vectorized)
//   72      : scalars + aq/Gram zero
//   73..328 : L -> Lh/Ll split (float4 -> ushort4)
//   329..456: Xq -> ABh/ABl rows 512.. (float4 -> ushort4)
__global__ __launch_bounds__(256) void k_prep(const float* __restrict__ diag,
                                              const float* __restrict__ low,
                                              const float* __restrict__ Xs,
                                              const float* __restrict__ Xq,
                                              const float* __restrict__ m,
                                              const float* __restrict__ kp,
                                              const float* __restrict__ nup,
                                              u16* __restrict__ Lh, u16* __restrict__ Ll,
                                              u16* __restrict__ ABh, u16* __restrict__ ABl,
                                              u16* __restrict__ Wh, u16* __restrict__ Wl,
                                              float* __restrict__ S, float* __restrict__ aq,
                                              float* __restrict__ Gram) {
  __shared__ float M[64][MPAD];
  int bid = blockIdx.x, tid = threadIdx.x;
  if (bid < 8) {
    int p = bid * 64;
    for (int idx = tid; idx < 4096; idx += 256) {
      int r = idx >> 6, c = idx & 63;
      float v;
      if (r == c)      v = fabsf(diag[p + r]);
      else if (r > c)  v = low[(size_t)(p + r) * D + p + c];
      else             v = 0.f;
      M[r][c] = v;
    }
    __syncthreads();
    inv64(M, tid);
    for (int idx = tid; idx < 1024; idx += 256) {
      int r = idx >> 4, c4 = (idx & 15) << 2;
      ushort4 hh, ll;
      split4(M[r][c4 + 0], M[r][c4 + 1], M[r][c4 + 2], M[r][c4 + 3], hh, ll);
      size_t gi = (size_t)(p + r) * D + p + c4;
      *reinterpret_cast<ushort4*>(Wh + gi) = hh;
      *reinterpret_cast<ushort4*>(Wl + gi) = ll;
    }
  } else if (bid < 72) {
    int c = bid - 8;
    if (tid < 128) {
      float kappa = kp[0];
      float kn = fabsf(kappa) + 1e-6f + 5.0f;
      float xw = 5.0f / kn;
      float mw = fabsf(kappa + 1e-6f) / kn;
      float sw = sqrtf((fabsf(kappa) + 1e-6f) / kn);
      const float is5 = 0.44721359549995793f;
      int d4 = tid;                       // float4 index; d = 4*tid
      float xs[5][4];
#pragma unroll
      for (int s = 0; s < 5; ++s) {
        float4 v = reinterpret_cast<const float4*>(Xs + (size_t)(c * 5 + s) * D)[d4];
        xs[s][0] = v.x; xs[s][1] = v.y; xs[s][2] = v.z; xs[s][3] = v.w;
      }
      float4 mvv = reinterpret_cast<const float4*>(m)[d4];
      float mv[4] = {mvv.x, mvv.y, mvv.z, mvv.w};
      float rows[8][4];
#pragma unroll
      for (int e = 0; e < 4; ++e) {
        float xm = (xs[0][e] + xs[1][e] + xs[2][e] + xs[3][e] + xs[4][e]) * 0.2f;
#pragma unroll
        for (int s = 0; s < 5; ++s) rows[s][e] = xs[s][e] * is5;
        rows[5][e] = sw * (xm - mv[e]);
        rows[6][e] = mw * mv[e] + xw * xm;
        rows[7][e] = 0.f;
      }
#pragma unroll
      for (int s = 0; s < 8; ++s) {
        ushort4 hh, ll;
        split4(rows[s][0], rows[s][1], rows[s][2], rows[s][3], hh, ll);
        size_t gi = (size_t)(c * 8 + s) * D + 4 * tid;
        *reinterpret_cast<ushort4*>(ABh + gi) = hh;
        *reinterpret_cast<ushort4*>(ABl + gi) = ll;
      }
    }
  } else if (bid == 72) {
    for (int i = tid; i < NQ; i += 256) aq[i] = 0.f;
    for (int i = tid; i < NC * 28; i += 256) Gram[i] = 0.f;
    if (tid >= 64) return;
    float part = 0.f;
    for (int i = tid; i < D; i += 64) part += logf(fabsf(diag[i]));
    part = wred(part);
    if (tid != 0) return;
    float lda = 2.f * part;
    float kappa = kp[0], nu = nup[0];
    float kn = fabsf(kappa) + 1e-6f + 5.0f;
    float sp = fmaxf(nu, (float)(D - 1) + 1e-6f) + 5.0f - (float)D + 2.0f;
    float bias_shared = lgammaf(0.5f * (sp + (float)D)) - lgammaf(0.5f * sp)
                      - 0.5f * (float)D * logf(sp);
    float scale = kn * sp / (kn + 1.0f);
    S[3] = bias_shared;
    S[8] = 1.f / scale;
    S[9] = (float)D * logf(scale) + lda;
    S[10] = 0.5f * (sp + (float)D);
    S[11] = 1.f / sp;
  } else if (bid < 329) {
    int t = (bid - 73) * 1024 + tid * 4;
    int i = t >> 9, j = t & 511;
    float4 lv = *reinterpret_cast<const float4*>(low + t);
    float a[4] = {lv.x, lv.y, lv.z, lv.w};
    float dv = diag[i];
    float o[4];
#pragma unroll
    for (int e = 0; e < 4; ++e) {
      int jj = j + e;
      o[e] = (i == jj) ? fabsf(dv) : (i > jj ? a[e] : 0.f);
    }
    ushort4 hh, ll;
    split4(o[0], o[1], o[2], o[3], hh, ll);
    *reinterpret_cast<ushort4*>(Lh + t) = hh;
    *reinterpret_cast<ushort4*>(Ll + t) = ll;
  } else {
    size_t base = (size_t)(bid - 329) * 8192;
#pragma unroll
    for (int it = 0; it < 8; ++it) {
      size_t idx = base + it * 1024 + tid * 4;
      float4 v = *reinterpret_cast<const float4*>(Xq + idx);
      ushort4 hh, ll;
      split4(v.x, v.y, v.z, v.w, hh, ll);
      *reinterpret_cast<ushort4*>(ABh + (size_t)512 * D + idx) = hh;
      *reinterpret_cast<ushort4*>(ABl + (size_t)512 * D + idx) = ll;
    }
  }
}

// W = L^{-1} column-panel solve, 64-row granularity (R10-proven).
// Panel J (0..15) owns W cols [32J,32J+32); i0 = J>>1. MFMA split-bf16 3-pass.
__global__ __launch_bounds__(256) void k_solve(const u16* __restrict__ Lh,
                                               const u16* __restrict__ Ll,
                                               u16* __restrict__ Wh,
                                               const u16* __restrict__ Wl) {
  __shared__ __align__(16) u16 XTh[32][520];
  __shared__ __align__(16) u16 XTl[32][520];
  __shared__ __align__(16) u16 STh[32][72];
  __shared__ __align__(16) u16 STl[32][72];
  int J = blockIdx.x;
  int i0 = J >> 1;
  int tid = threadIdx.x, w = tid >> 6, lane = tid & 63;
  int lr = lane & 15, kq = lane >> 4;
  for (int idx = tid; idx < 64 * 32; idx += 256) {
    int r = idx >> 5, c = idx & 31;
    size_t gi = (size_t)(64 * i0 + r) * D + 64 * i0 + (J & 1) * 32 + c;
    XTh[c][64 * i0 + r] = Wh[gi];
    XTl[c][64 * i0 + r] = Wl[gi];
  }
  __syncthreads();
  for (int i = i0 + 1; i < 8; ++i) {
    f4 acc[2];
    acc[0] = (f4){0.f, 0.f, 0.f, 0.f};
    acc[1] = (f4){0.f, 0.f, 0.f, 0.f};
    for (int k = i0; k < i; ++k) {
#pragma unroll
      for (int kk = 0; kk < 2; ++kk) {
        size_t ga = (size_t)(64 * i + w * 16 + lr) * D + 64 * k + kk * 32 + kq * 8;
        bf8 ah = *reinterpret_cast<const bf8*>(Lh + ga);
        bf8 al = *reinterpret_cast<const bf8*>(Ll + ga);
#pragma unroll
        for (int nf = 0; nf < 2; ++nf) {
          bf8 bh = *reinterpret_cast<const bf8*>(&XTh[nf * 16 + lr][64 * k + kk * 32 + kq * 8]);
          bf8 bl = *reinterpret_cast<const bf8*>(&XTl[nf * 16 + lr][64 * k + kk * 32 + kq * 8]);
          acc[nf] = __builtin_amdgcn_mfma_f32_16x16x32_bf16(ah, bh, acc[nf], 0, 0, 0);
          acc[nf] = __builtin_amdgcn_mfma_f32_16x16x32_bf16(al, bh, acc[nf], 0, 0, 0);
          acc[nf] = __builtin_amdgcn_mfma_f32_16x16x32_bf16(ah, bl, acc[nf], 0, 0, 0);
        }
      }
    }
#pragma unroll
    for (int nf = 0; nf < 2; ++nf)
#pragma unroll
      for (int reg = 0; reg < 4; ++reg) {
        float v = -acc[nf][reg];
        u16 hh, ll; split2(v, hh, ll);
        int c = nf * 16 + lr, r = w * 16 + kq * 4 + reg;
        STh[c][r] = hh; STl[c][r] = ll;
      }
    __syncthreads();
    f4 acc2[2];
    acc2[0] = (f4){0.f, 0.f, 0.f, 0.f};
    acc2[1] = (f4){0.f, 0.f, 0.f, 0.f};
#pragma unroll
    for (int kk = 0; kk < 2; ++kk) {
      size_t ga = (size_t)(64 * i + w * 16 + lr) * D + 64 * i + kk * 32 + kq * 8;
      bf8 ah = *reinterpret_cast<const bf8*>(Wh + ga);
      bf8 al = *reinterpret_cast<const bf8*>(Wl + ga);
#pragma unroll
      for (int nf = 0; nf < 2; ++nf) {
        bf8 bh = *reinterpret_cast<const bf8*>(&STh[nf * 16 + lr][kk * 32 + kq * 8]);
        bf8 bl = *reinterpret_cast<const bf8*>(&STl[nf * 16 + lr][kk * 32 + kq * 8]);
        acc2[nf] = __builtin_amdgcn_mfma_f32_16x16x32_bf16(ah, bh, acc2[nf], 0, 0, 0);
        acc2[nf] = __builtin_amdgcn_mfma_f32_16x16x32_bf16(ah, bl, acc2[nf], 0, 0, 0);
        acc2[nf] = __builtin_amdgcn_mfma_f32_16x16x32_bf16(al, bh, acc2[nf], 0, 0, 0);
      }
    }
#pragma unroll
    for (int nf = 0; nf < 2; ++nf)
#pragma unroll
      for (int reg = 0; reg < 4; ++reg) {
        float v = acc2[nf][reg];
        u16 hh, ll; split2(v, hh, ll);
        int r = w * 16 + kq * 4 + reg, c = nf * 16 + lr;
        Wh[(size_t)(64 * i + r) * D + 32 * J + c] = hh;
        XTh[c][64 * i + r] = hh; XTl[c][64 * i + r] = ll;
      }
    __syncthreads();
  }
}

// GEMM1 (MFMA split-bf16, 2-pass hh+lh): YY = [Ubp;Xq] @ W^T, tri-clipped.
// R10-proven grid (40,8). Fused: YYh (all), YYl (Y rows), aq, class Grams.
__global__ __launch_bounds__(256) void k_mf1(const u16* __restrict__ ABh, const u16* __restrict__ ABl,
                                             const u16* __restrict__ Wh,
                                             u16* __restrict__ YYh, u16* __restrict__ YYl,
                                             float* __restrict__ Gram, float* __restrict__ aq) {
  __shared__ float Csh[64][68];
  int tid = threadIdx.x, w = tid >> 6, lane = tid & 63;
  int m0 = blockIdx.x * 64 + w * 16;
  int bn = blockIdx.y * 64;
  int lr = lane & 15, kof = (lane >> 4) * 8;
  const u16* ah_p = ABh + (size_t)(m0 + lr) * D + kof;
  const u16* al_p = ABl + (size_t)(m0 + lr) * D + kof;
  const u16* bh_p = Wh + (size_t)(bn + lr) * D + kof;
  f4 acc[4];
#pragma unroll
  for (int nf = 0; nf < 4; ++nf) acc[nf] = (f4){0.f, 0.f, 0.f, 0.f};
  int Klim = bn + 64;
#pragma unroll 2
  for (int k0 = 0; k0 < Klim; k0 += 32) {
    bf8 ah = *reinterpret_cast<const bf8*>(ah_p + k0);
    bf8 al = *reinterpret_cast<const bf8*>(al_p + k0);
    bf8 bh[4];
#pragma unroll
    for (int nf = 0; nf < 4; ++nf)
      bh[nf] = *reinterpret_cast<const bf8*>(bh_p + (size_t)nf * 16 * D + k0);
#pragma unroll
    for (int nf = 0; nf < 4; ++nf)
      acc[nf] = __builtin_amdgcn_mfma_f32_16x16x32_bf16(ah, bh[nf], acc[nf], 0, 0, 0);
#pragma unroll
    for (int nf = 0; nf < 4; ++nf)
      acc[nf] = __builtin_amdgcn_mfma_f32_16x16x32_bf16(al, bh[nf], acc[nf], 0, 0, 0);
  }
  int rbase = m0 + ((lane >> 4) << 2);   // C layout: row=(lane>>4)*4+reg, col=lane&15
#pragma unroll
  for (int reg = 0; reg < 4; ++reg) {
    int row = rbase + reg;
    float sq = 0.f;
#pragma unroll
    for (int nf = 0; nf < 4; ++nf) {
      float v = acc[nf][reg];
      size_t gi = (size_t)row * D + bn + nf * 16 + lr;
      u16 hh, ll; split2(v, hh, ll);
      YYh[gi] = hh;
      if (row >= 512) YYl[gi] = ll;
      sq += v * v;
    }
    if (row >= 512) {
#pragma unroll
      for (int mk = 1; mk < 16; mk <<= 1) sq += __shfl_xor(sq, mk);
      if (lr == 0) atomicAdd(&aq[row - 512], sq);
    }
  }
  if (blockIdx.x < 8) {
    // partial 7x7 Grams for this block's 8 classes over its 64-col strip
#pragma unroll
    for (int reg = 0; reg < 4; ++reg)
#pragma unroll
      for (int nf = 0; nf < 4; ++nf)
        Csh[w * 16 + ((lane >> 4) << 2) + reg][nf * 16 + lr] = acc[nf][reg];
    __syncthreads();
    if (tid < 224) {
      const int PI[28] = {0,0,0,0,0,0,0, 1,1,1,1,1,1, 2,2,2,2,2, 3,3,3,3, 4,4,4, 5,5, 6};
      const int PJ[28] = {0,1,2,3,4,5,6, 1,2,3,4,5,6, 2,3,4,5,6, 3,4,5,6, 4,5,6, 5,6, 6};
      int cl = tid / 28, p = tid % 28;
      const float* ri = Csh[cl * 8 + PI[p]];
      const float* rj = Csh[cl * 8 + PJ[p]];
      float s = 0.f;
#pragma unroll
      for (int c4 = 0; c4 < 64; c4 += 4) {
        float4 a = *reinterpret_cast<const float4*>(&ri[c4]);
        float4 b = *reinterpret_cast<const float4*>(&rj[c4]);
        s += a.x * b.x + a.y * b.y + a.z * b.z + a.w * b.w;
      }
      atomicAdd(&Gram[(blockIdx.x * 8 + cl) * 28 + p], s);
    }
  }
}

// GEMM2 (MFMA split-bf16, 2-pass) + per-block Cholesky prologue + fused epilogue.
__global__ __launch_bounds__(256) void k_mf2(const u16* __restrict__ Yh, const u16* __restrict__ Yl,
                                             const u16* __restrict__ Bh,
                                             const float* __restrict__ aq,
                                             const float* __restrict__ Gram,
                                             const float* __restrict__ S,
                                             float* __restrict__ out) {
  __shared__ float Csh[4][16][68];
  __shared__ float PRo[8][15], PRd[8][6], Psv[8][6], Pb[8], Ph[8];
  int tid = threadIdx.x, w = tid >> 6, lane = tid & 63;
  int m0 = blockIdx.x * 64 + w * 16;
  int bn = blockIdx.y * 64;
  int lr = lane & 15, kof = (lane >> 4) * 8;
  const u16* ah_p = Yh + (size_t)(m0 + lr) * D + kof;
  const u16* al_p = Yl + (size_t)(m0 + lr) * D + kof;
  const u16* bh_p = Bh + (size_t)(bn + lr) * D + kof;
  f4 acc[4];
#pragma unroll
  for (int nf = 0; nf < 4; ++nf) acc[nf] = (f4){0.f, 0.f, 0.f, 0.f};
#pragma unroll 2
  for (int k0 = 0; k0 < D; k0 += 32) {
    bf8 ah = *reinterpret_cast<const bf8*>(ah_p + k0);
    bf8 al = *reinterpret_cast<const bf8*>(al_p + k0);
    bf8 bh[4];
#pragma unroll
    for (int nf = 0; nf < 4; ++nf)
      bh[nf] = *reinterpret_cast<const bf8*>(bh_p + (size_t)nf * 16 * D + k0);
#pragma unroll
    for (int nf = 0; nf < 4; ++nf)
      acc[nf] = __builtin_amdgcn_mfma_f32_16x16x32_bf16(ah, bh[nf], acc[nf], 0, 0, 0);
#pragma unroll
    for (int nf = 0; nf < 4; ++nf)
      acc[nf] = __builtin_amdgcn_mfma_f32_16x16x32_bf16(al, bh[nf], acc[nf], 0, 0, 0);
  }
#pragma unroll
  for (int reg = 0; reg < 4; ++reg)
#pragma unroll
    for (int nf = 0; nf < 4; ++nf)
      Csh[w][((lane >> 4) << 2) + reg][nf * 16 + lr] = acc[nf][reg];
  if (tid < 8) {
    int c = blockIdx.y * 8 + tid;
    float Gv[28];
#pragma unroll
    for (int p = 0; p < 28; ++p) Gv[p] = Gram[c * 28 + p];
    float R[6][6];
    float logdetM = 0.f;
#pragma unroll
    for (int i = 0; i < 6; ++i) {
      float s = Gv[GIX(i, i)] + 1.f;
#pragma unroll
      for (int k = 0; k < i; ++k) s -= R[i][k] * R[i][k];
      float rii = sqrtf(s);
      R[i][i] = rii;
      logdetM += logf(rii);
      float inv = 1.f / rii;
      PRd[tid][i] = inv;
#pragma unroll
      for (int r = i + 1; r < 6; ++r) {
        float s2 = Gv[GIX(i, r)];
#pragma unroll
        for (int k = 0; k < i; ++k) s2 -= R[r][k] * R[i][k];
        R[r][i] = s2 * inv;
      }
    }
#pragma unroll
    for (int i = 1; i < 6; ++i)
#pragma unroll
      for (int k = 0; k < i; ++k)
        PRo[tid][i * (i - 1) / 2 + k] = R[i][k];
#pragma unroll
    for (int j = 0; j < 6; ++j) Psv[tid][j] = Gv[GIX(j, 6)];
    Ph[tid] = Gv[27];
    Pb[tid] = S[3] - 0.5f * (S[9] + 2.f * logdetM);
  }
  __syncthreads();
  float s8 = S[8], s10 = S[10], s11 = S[11];
  int r = lr;
  int q = m0 + r;
  float aqv = aq[q];
#pragma unroll
  for (int cc = 0; cc < 2; ++cc) {
    int cl = ((lane >> 4) << 1) + cc;
    const float* t = &Csh[w][r][cl * 8];
    float e[6];
#pragma unroll
    for (int j = 0; j < 6; ++j) e[j] = t[j] - Psv[cl][j];
    const float* o = PRo[cl];
    const float* dg = PRd[cl];
    float z0 = e[0] * dg[0];
    float z1 = (e[1] - o[0] * z0) * dg[1];
    float z2 = (e[2] - o[1] * z0 - o[2] * z1) * dg[2];
    float z3 = (e[3] - o[3] * z0 - o[4] * z1 - o[5] * z2) * dg[3];
    float z4 = (e[4] - o[6] * z0 - o[7] * z1 - o[8] * z2 - o[9] * z3) * dg[4];
    float z5 = (e[5] - o[10] * z0 - o[11] * z1 - o[12] * z2 - o[13] * z3 - o[14] * z4) * dg[5];
    float quad = z0 * z0 + z1 * z1 + z2 * z2 + z3 * z3 + z4 * z4 + z5 * z5;
    float dist = (aqv - 2.f * t[6] + Ph[cl] - quad) * s8;
    out[(size_t)q * NC + blockIdx.y * 8 + cl] = Pb[cl] - s10 * log1pf(dist * s11);
  }
}

extern "C" void kernel_launch(void* const* d_in, const int* in_sizes, int n_in,
                              void* d_out, int out_size, void* d_ws, size_t ws_size,
                              hipStream_t stream) {
  const float* Xs   = (const float*)d_in[0];
  const float* Xq   = (const float*)d_in[2];
  const float* m    = (const float*)d_in[3];
  const float* kap  = (const float*)d_in[4];
  const float* nu   = (const float*)d_in[5];
  const float* diag = (const float*)d_in[6];
  const float* low  = (const float*)d_in[7];
  float* ws = (float*)d_ws;

  float* S    = ws + OFF_S;
  u16*   ABh  = (u16*)(ws + OFF_ABH);
  u16*   ABl  = (u16*)(ws + OFF_ABL);
  u16*   Lh   = (u16*)(ws + OFF_LH);
  u16*   Ll   = (u16*)(ws + OFF_LL);
  u16*   Wh   = (u16*)(ws + OFF_WH);
  u16*   Wl   = (u16*)(ws + OFF_WL);
  u16*   YYh  = (u16*)(ws + OFF_YYH);
  u16*   YYl  = (u16*)(ws + OFF_YYL);
  float* aq   = ws + OFF_AQ;
  float* Gram = ws + OFF_GRAM;

  hipLaunchKernelGGL(k_prep, dim3(457), dim3(256), 0, stream,
                     diag, low, Xs, Xq, m, kap, nu, Lh, Ll, ABh, ABl, Wh, Wl, S, aq, Gram);
  hipLaunchKernelGGL(k_solve, dim3(16), dim3(256), 0, stream, Lh, Ll, Wh, Wl);
  // GEMM1: YY = [Ubp;Xq] @ W^T (tri-clipped) + aq + class Grams
  hipLaunchKernelGGL(k_mf1, dim3(40, 8), dim3(256), 0, stream,
                     ABh, ABl, Wh, YYh, YYl, Gram, aq);
  // GEMM2: out = epilogue(Y @ UWp^T) with per-block Cholesky prologue
  hipLaunchKernelGGL(k_mf2, dim3(32, 8), dim3(256), 0, stream,
                     YYh + (size_t)512 * D, YYl + (size_t)512 * D, YYh,
                     aq, Gram, S, (float*)d_out);
}